// Round 13
// baseline (11046.593 us; speedup 1.0000x reference)
//
#include <hip/hip_runtime.h>
#include <math.h>

// LSTMModel: 2048 sequential steps, 2x LSTMCell(H=512), LN(64) front, fc(512->1).
// R12 = R9 structure + SOUND pipelined polling. R8/R11 lesson (3 strikes): split
// issue/wait across separate asm statements is unsound (regalloc copies in-flight
// dest regs). Fix: each poller is ONE asm block with internal labels/branches.
// - poll_pp4 (L0): ping-pong two 4-load sets on one packet; vmcnt(4) checks the
//   older set while the newer flies -> detect granularity ~RTT/2.
// - poll_pp8 (L1): ping-pong two 8-load sets covering BOTH packets (h0+h1)
//   concurrently -> 1 RTT per cycle (kills R9's serial 2xRTT) + RTT/2 detect.
// Poison check: v_max_u32 reduce + v_cmp_eq_u32 vcc,-1 + s_cbranch_vccz
// (valid h bits are never 0xFFFFFFFF; poison->value is monotonic).

#define H      512
#define G4     2048
#define WIN    64
#define STEPS  2048
#define NL0B   64      // layer-0 blocks (8 units each)
#define NL1B   128     // layer-1 blocks (4 units each)
#define TPB    512
#define POISON 0xFFFFFFFFu

typedef unsigned int u32x4 __attribute__((ext_vector_type(4)));
typedef float        f32x4 __attribute__((ext_vector_type(4)));

__device__ __forceinline__ float sigf(float x)     { return 1.0f / (1.0f + __expf(-x)); }
__device__ __forceinline__ float tanhfast(float x) { return 2.0f / (1.0f + __expf(-2.0f * x)) - 1.0f; }

__device__ __forceinline__ void st1_sc01(unsigned int* p, unsigned int v) {
    asm volatile("global_store_dword %0, %1, off sc0 sc1" :: "v"(p), "v"(v));
}

// ---- ping-pong poll of one 16B packet (4 dwords), single asm block ----
__device__ __forceinline__ u32x4 poll_pp4(const unsigned int* p) {
    unsigned int a0, a1, a2, a3, b0, b1, b2, b3, t;
    asm volatile(
        "global_load_dword %[a0], %[pp], off sc0 sc1\n\t"
        "global_load_dword %[a1], %[pp], off offset:4 sc0 sc1\n\t"
        "global_load_dword %[a2], %[pp], off offset:8 sc0 sc1\n\t"
        "global_load_dword %[a3], %[pp], off offset:12 sc0 sc1\n\t"
        "global_load_dword %[b0], %[pp], off sc0 sc1\n\t"
        "global_load_dword %[b1], %[pp], off offset:4 sc0 sc1\n\t"
        "global_load_dword %[b2], %[pp], off offset:8 sc0 sc1\n\t"
        "global_load_dword %[b3], %[pp], off offset:12 sc0 sc1\n\t"
        "LTOP%=:\n\t"
        "s_waitcnt vmcnt(4)\n\t"                 // oldest set (A) landed
        "v_max_u32 %[t], %[a0], %[a1]\n\t"
        "v_max_u32 %[t], %[t], %[a2]\n\t"
        "v_max_u32 %[t], %[t], %[a3]\n\t"
        "v_cmp_eq_u32 vcc, -1, %[t]\n\t"
        "s_cbranch_vccz LDA%=\n\t"
        "global_load_dword %[a0], %[pp], off sc0 sc1\n\t"
        "global_load_dword %[a1], %[pp], off offset:4 sc0 sc1\n\t"
        "global_load_dword %[a2], %[pp], off offset:8 sc0 sc1\n\t"
        "global_load_dword %[a3], %[pp], off offset:12 sc0 sc1\n\t"
        "s_waitcnt vmcnt(4)\n\t"                 // B landed (A' flying)
        "v_max_u32 %[t], %[b0], %[b1]\n\t"
        "v_max_u32 %[t], %[t], %[b2]\n\t"
        "v_max_u32 %[t], %[t], %[b3]\n\t"
        "v_cmp_eq_u32 vcc, -1, %[t]\n\t"
        "s_cbranch_vccz LDB%=\n\t"
        "global_load_dword %[b0], %[pp], off sc0 sc1\n\t"
        "global_load_dword %[b1], %[pp], off offset:4 sc0 sc1\n\t"
        "global_load_dword %[b2], %[pp], off offset:8 sc0 sc1\n\t"
        "global_load_dword %[b3], %[pp], off offset:12 sc0 sc1\n\t"
        "s_branch LTOP%=\n\t"
        "LDA%=:\n\t"
        "s_waitcnt vmcnt(0)\n\t"                 // drain B set
        "s_branch LEND%=\n\t"
        "LDB%=:\n\t"
        "s_waitcnt vmcnt(0)\n\t"                 // drain A' set
        "v_mov_b32 %[a0], %[b0]\n\t"
        "v_mov_b32 %[a1], %[b1]\n\t"
        "v_mov_b32 %[a2], %[b2]\n\t"
        "v_mov_b32 %[a3], %[b3]\n\t"
        "LEND%=:"
        : [a0]"=&v"(a0), [a1]"=&v"(a1), [a2]"=&v"(a2), [a3]"=&v"(a3),
          [b0]"=&v"(b0), [b1]"=&v"(b1), [b2]"=&v"(b2), [b3]"=&v"(b3),
          [t]"=&v"(t)
        : [pp]"v"(p)
        : "vcc");
    u32x4 v; v.x = a0; v.y = a1; v.z = a2; v.w = a3;
    return v;
}

// ---- ping-pong poll of TWO 16B packets concurrently (8 dwords), one asm block ----
__device__ __forceinline__ void poll_pp8(const unsigned int* pa, const unsigned int* pb,
                                         u32x4& va, u32x4& vb) {
    unsigned int a0,a1,a2,a3,a4,a5,a6,a7, b0,b1,b2,b3,b4,b5,b6,b7, t;
    asm volatile(
        "global_load_dword %[a0], %[qa], off sc0 sc1\n\t"
        "global_load_dword %[a1], %[qa], off offset:4 sc0 sc1\n\t"
        "global_load_dword %[a2], %[qa], off offset:8 sc0 sc1\n\t"
        "global_load_dword %[a3], %[qa], off offset:12 sc0 sc1\n\t"
        "global_load_dword %[a4], %[qb], off sc0 sc1\n\t"
        "global_load_dword %[a5], %[qb], off offset:4 sc0 sc1\n\t"
        "global_load_dword %[a6], %[qb], off offset:8 sc0 sc1\n\t"
        "global_load_dword %[a7], %[qb], off offset:12 sc0 sc1\n\t"
        "global_load_dword %[b0], %[qa], off sc0 sc1\n\t"
        "global_load_dword %[b1], %[qa], off offset:4 sc0 sc1\n\t"
        "global_load_dword %[b2], %[qa], off offset:8 sc0 sc1\n\t"
        "global_load_dword %[b3], %[qa], off offset:12 sc0 sc1\n\t"
        "global_load_dword %[b4], %[qb], off sc0 sc1\n\t"
        "global_load_dword %[b5], %[qb], off offset:4 sc0 sc1\n\t"
        "global_load_dword %[b6], %[qb], off offset:8 sc0 sc1\n\t"
        "global_load_dword %[b7], %[qb], off offset:12 sc0 sc1\n\t"
        "LTOP%=:\n\t"
        "s_waitcnt vmcnt(8)\n\t"                 // oldest super-set (A) landed
        "v_max_u32 %[t], %[a0], %[a1]\n\t"
        "v_max_u32 %[t], %[t], %[a2]\n\t"
        "v_max_u32 %[t], %[t], %[a3]\n\t"
        "v_max_u32 %[t], %[t], %[a4]\n\t"
        "v_max_u32 %[t], %[t], %[a5]\n\t"
        "v_max_u32 %[t], %[t], %[a6]\n\t"
        "v_max_u32 %[t], %[t], %[a7]\n\t"
        "v_cmp_eq_u32 vcc, -1, %[t]\n\t"
        "s_cbranch_vccz LDA%=\n\t"
        "global_load_dword %[a0], %[qa], off sc0 sc1\n\t"
        "global_load_dword %[a1], %[qa], off offset:4 sc0 sc1\n\t"
        "global_load_dword %[a2], %[qa], off offset:8 sc0 sc1\n\t"
        "global_load_dword %[a3], %[qa], off offset:12 sc0 sc1\n\t"
        "global_load_dword %[a4], %[qb], off sc0 sc1\n\t"
        "global_load_dword %[a5], %[qb], off offset:4 sc0 sc1\n\t"
        "global_load_dword %[a6], %[qb], off offset:8 sc0 sc1\n\t"
        "global_load_dword %[a7], %[qb], off offset:12 sc0 sc1\n\t"
        "s_waitcnt vmcnt(8)\n\t"                 // B landed (A' flying)
        "v_max_u32 %[t], %[b0], %[b1]\n\t"
        "v_max_u32 %[t], %[t], %[b2]\n\t"
        "v_max_u32 %[t], %[t], %[b3]\n\t"
        "v_max_u32 %[t], %[t], %[b4]\n\t"
        "v_max_u32 %[t], %[t], %[b5]\n\t"
        "v_max_u32 %[t], %[t], %[b6]\n\t"
        "v_max_u32 %[t], %[t], %[b7]\n\t"
        "v_cmp_eq_u32 vcc, -1, %[t]\n\t"
        "s_cbranch_vccz LDB%=\n\t"
        "global_load_dword %[b0], %[qa], off sc0 sc1\n\t"
        "global_load_dword %[b1], %[qa], off offset:4 sc0 sc1\n\t"
        "global_load_dword %[b2], %[qa], off offset:8 sc0 sc1\n\t"
        "global_load_dword %[b3], %[qa], off offset:12 sc0 sc1\n\t"
        "global_load_dword %[b4], %[qb], off sc0 sc1\n\t"
        "global_load_dword %[b5], %[qb], off offset:4 sc0 sc1\n\t"
        "global_load_dword %[b6], %[qb], off offset:8 sc0 sc1\n\t"
        "global_load_dword %[b7], %[qb], off offset:12 sc0 sc1\n\t"
        "s_branch LTOP%=\n\t"
        "LDA%=:\n\t"
        "s_waitcnt vmcnt(0)\n\t"
        "s_branch LEND%=\n\t"
        "LDB%=:\n\t"
        "s_waitcnt vmcnt(0)\n\t"
        "v_mov_b32 %[a0], %[b0]\n\t"
        "v_mov_b32 %[a1], %[b1]\n\t"
        "v_mov_b32 %[a2], %[b2]\n\t"
        "v_mov_b32 %[a3], %[b3]\n\t"
        "v_mov_b32 %[a4], %[b4]\n\t"
        "v_mov_b32 %[a5], %[b5]\n\t"
        "v_mov_b32 %[a6], %[b6]\n\t"
        "v_mov_b32 %[a7], %[b7]\n\t"
        "LEND%=:"
        : [a0]"=&v"(a0), [a1]"=&v"(a1), [a2]"=&v"(a2), [a3]"=&v"(a3),
          [a4]"=&v"(a4), [a5]"=&v"(a5), [a6]"=&v"(a6), [a7]"=&v"(a7),
          [b0]"=&v"(b0), [b1]"=&v"(b1), [b2]"=&v"(b2), [b3]"=&v"(b3),
          [b4]"=&v"(b4), [b5]"=&v"(b5), [b6]"=&v"(b6), [b7]"=&v"(b7),
          [t]"=&v"(t)
        : [qa]"v"(pa), [qb]"v"(pb)
        : "vcc");
    va.x = a0; va.y = a1; va.z = a2; va.w = a3;
    vb.x = a4; vb.y = a5; vb.z = a6; vb.w = a7;
}

__device__ __forceinline__ void lds_put4(float* dst, u32x4 v) {
    float4 f;
    f.x = __uint_as_float(v.x); f.y = __uint_as_float(v.y);
    f.z = __uint_as_float(v.z); f.w = __uint_as_float(v.w);
    *(float4*)dst = f;
}

// ---------------- LayerNorm over sliding windows (parallel over t) ----------------
__global__ void ln_kernel(const float* __restrict__ batch, const float* __restrict__ lnw,
                          const float* __restrict__ lnb, float* __restrict__ lnx) {
    int wave = threadIdx.x >> 6;
    int lane = threadIdx.x & 63;
    int t = blockIdx.x * 4 + wave;
    int src = t - 63 + lane;
    float v = (src >= 0) ? batch[src] : 0.0f;
    float s = v, ss = v * v;
    #pragma unroll
    for (int m = 32; m >= 1; m >>= 1) { s += __shfl_xor(s, m); ss += __shfl_xor(ss, m); }
    float mu   = s * (1.0f / 64.0f);
    float var  = ss * (1.0f / 64.0f) - mu * mu;
    float rstd = rsqrtf(var + 1e-5f);
    lnx[t * WIN + lane] = (v - mu) * rstd * lnw[lane] + lnb[lane];
}

// ---- precomp, UNIT-MAJOR layout: pre[t*2048 + unit*4 + gate] ----
__global__ __launch_bounds__(256) void precomp_kernel(
    const float* __restrict__ Wih0, const float* __restrict__ bih0,
    const float* __restrict__ bhh0, const float* __restrict__ lnx,
    float* __restrict__ pre) {
    __shared__ float Wt[64][65];
    __shared__ float Xt[64][64];
    int r0 = blockIdx.x * 64;
    int t0 = blockIdx.y * 64;
    for (int i = threadIdx.x; i < 4096; i += 256) Wt[i >> 6][i & 63] = Wih0[r0 * 64 + i];
    for (int i = threadIdx.x; i < 4096; i += 256) Xt[i >> 6][i & 63] = lnx[t0 * 64 + i];
    __syncthreads();
    int lane = threadIdx.x & 63;
    int wv   = threadIdx.x >> 6;
    int row  = r0 + lane;                      // gate-major: gate*512 + unit
    int oidx = (row & 511) * 4 + (row >> 9);   // unit-major: unit*4 + gate
    float bias = bih0[row] + bhh0[row];
    for (int j = 0; j < 16; ++j) {
        int tl = wv * 16 + j;
        float acc = bias;
        #pragma unroll 8
        for (int k = 0; k < 64; ++k) acc += Wt[lane][k] * Xt[tl][k];
        pre[(size_t)(t0 + tl) * G4 + oidx] = acc;
    }
}

// ---------------- persistent recurrent kernel ----------------
__global__ __launch_bounds__(TPB) void recur_kernel(
    const float* __restrict__ Whh0,
    const float* __restrict__ Wih1, const float* __restrict__ Whh1,
    const float* __restrict__ bih1, const float* __restrict__ bhh1,
    const float* __restrict__ pre,
    unsigned int* h0u, unsigned int* h1u) { // [STEPS+1][H] histories, NaN-poisoned
    const int tid = threadIdx.x;
    const int s   = tid & 31;
    const int LG  = tid >> 5;    // 16 lane-groups of 32

    if (blockIdx.x < NL0B) {
        // -------- layer-0: 8 units/block; unit = wave; 2 rows/lane-group --------
        __shared__ float hA[2][H];
        const int u0 = blockIdx.x * 8;
        const int u  = tid >> 6;              // wave index = unit-local
        float w0[2][16];
        #pragma unroll
        for (int j = 0; j < 2; ++j) {
            int r   = 2 * LG + j;
            int row = (r & 3) * H + u0 + (r >> 2);
            #pragma unroll
            for (int i = 0; i < 16; ++i) w0[j][i] = Whh0[(size_t)row * H + i * 32 + s];
        }
        float c0 = 0.0f;

        for (int t = 0; t < STEPS; ++t) {
            const int pb = t & 1;
            // pre for this wave's unit (same addr across wave -> broadcast)
            f32x4 prv = *(const f32x4*)(pre + (size_t)t * G4 + (u0 + u) * 4);
            if (tid < 128) {
                if (t > 0) {
                    u32x4 v = poll_pp4(h0u + (size_t)t * H + tid * 4);
                    lds_put4(&hA[pb][tid * 4], v);
                } else {
                    *(float4*)&hA[pb][tid * 4] = make_float4(0.f, 0.f, 0.f, 0.f);
                }
            }
            __syncthreads();

            float acc0 = 0.0f, acc1 = 0.0f;
            #pragma unroll
            for (int i = 0; i < 16; ++i) {
                float hv = hA[pb][i * 32 + s];
                acc0 += w0[0][i] * hv;
                acc1 += w0[1][i] * hv;
            }
            #pragma unroll
            for (int m = 16; m >= 1; m >>= 1) {
                acc0 += __shfl_xor(acc0, m);
                acc1 += __shfl_xor(acc1, m);
            }
            // lower half-wave group: gates i,f ; upper (lane 32): g,o
            float gacc = __shfl(acc0, 32);
            float oacc = __shfl(acc1, 32);
            if ((tid & 63) == 0) {
                float iv = sigf(acc0 + prv.x);
                float fv = sigf(acc1 + prv.y);
                float gv = tanhfast(gacc + prv.z);
                float ov = sigf(oacc + prv.w);
                c0 = fv * c0 + iv * gv;
                float hnew = ov * tanhfast(c0);
                st1_sc01(h0u + (size_t)(t + 1) * H + u0 + u, __float_as_uint(hnew));
            }
        }
    } else {
        // -------- layer-1: 4 units/block; 1 row/lane-group; LDS gate exchange --------
        __shared__ float hA2[2][H];
        __shared__ float hB2[2][H];
        __shared__ float glds[16];
        const int b1 = blockIdx.x - NL0B;
        const int u0 = b1 * 4;
        const int row = (LG & 3) * H + u0 + (LG >> 2);
        float w1[16], w2[16];
        #pragma unroll
        for (int i = 0; i < 16; ++i) {
            w1[i] = Wih1[(size_t)row * H + i * 32 + s];
            w2[i] = Whh1[(size_t)row * H + i * 32 + s];
        }
        const float rbias = bih1[row] + bhh1[row];
        float c1 = 0.0f;

        for (int t = 0; t < STEPS; ++t) {
            const int pb = t & 1;
            if (tid < 128) {
                const unsigned int* pa = h0u + (size_t)(t + 1) * H + tid * 4;
                if (t > 0) {
                    u32x4 va, vb;
                    poll_pp8(pa, h1u + (size_t)t * H + tid * 4, va, vb);
                    lds_put4(&hA2[pb][tid * 4], va);
                    lds_put4(&hB2[pb][tid * 4], vb);
                } else {
                    u32x4 va = poll_pp4(pa);
                    lds_put4(&hA2[pb][tid * 4], va);
                    *(float4*)&hB2[pb][tid * 4] = make_float4(0.f, 0.f, 0.f, 0.f);
                }
            }
            __syncthreads();

            float acc = 0.0f;
            #pragma unroll
            for (int i = 0; i < 16; ++i)
                acc += w1[i] * hA2[pb][i * 32 + s] + w2[i] * hB2[pb][i * 32 + s];
            #pragma unroll
            for (int m = 16; m >= 1; m >>= 1) acc += __shfl_xor(acc, m);
            if (s == 0) glds[LG] = acc + rbias;
            __syncthreads();
            if (tid < 4) {
                float iv = sigf(glds[4 * tid + 0]);
                float fv = sigf(glds[4 * tid + 1]);
                float gv = tanhfast(glds[4 * tid + 2]);
                float ov = sigf(glds[4 * tid + 3]);
                c1 = fv * c1 + iv * gv;
                float hnew = ov * tanhfast(c1);
                st1_sc01(h1u + (size_t)(t + 1) * H + u0 + tid, __float_as_uint(hnew));
            }
        }
    }
}

// ---------------- out[t] = fc(relu(h1[t+1])) from the h1 history ----------------
__global__ __launch_bounds__(TPB) void reduce_out(
    const unsigned int* __restrict__ h1u, const float* __restrict__ fcw,
    const float* __restrict__ fcb, float* __restrict__ out) {
    int t = blockIdx.x;
    int tid = threadIdx.x;               // 512 threads
    float h = __uint_as_float(h1u[(size_t)(t + 1) * H + tid]);
    float v = fmaxf(h, 0.0f) * fcw[tid];
    #pragma unroll
    for (int m = 32; m >= 1; m >>= 1) v += __shfl_xor(v, m);
    __shared__ float ws8[8];
    if ((tid & 63) == 0) ws8[tid >> 6] = v;
    __syncthreads();
    if (tid == 0) {
        float ssum = 0.0f;
        #pragma unroll
        for (int i = 0; i < 8; ++i) ssum += ws8[i];
        out[t] = ssum + fcb[0];
    }
}

extern "C" void kernel_launch(void* const* d_in, const int* in_sizes, int n_in,
                              void* d_out, int out_size, void* d_ws, size_t ws_size,
                              hipStream_t stream) {
    const float* batch = (const float*)d_in[0];
    const float* Wih0  = (const float*)d_in[1];
    const float* Whh0  = (const float*)d_in[2];
    const float* bih0  = (const float*)d_in[3];
    const float* bhh0  = (const float*)d_in[4];
    const float* Wih1  = (const float*)d_in[5];
    const float* Whh1  = (const float*)d_in[6];
    const float* bih1  = (const float*)d_in[7];
    const float* bhh1  = (const float*)d_in[8];
    const float* lnw   = (const float*)d_in[9];
    const float* lnb   = (const float*)d_in[10];
    const float* fcw   = (const float*)d_in[11];
    const float* fcb   = (const float*)d_in[12];
    float* out = (float*)d_out;

    // workspace layout (~17 MB)
    float*        ws   = (float*)d_ws;
    float*        pre  = ws;                                   // 2048*2048 (16 MB)
    float*        lnx  = pre + (size_t)STEPS * G4;             // 2048*64
    unsigned int* h0u  = (unsigned int*)(lnx + (size_t)STEPS * WIN);  // 2049*512
    unsigned int* h1u  = h0u + (size_t)(STEPS + 1) * H;        // 2049*512

    // poison both h histories (NaN pattern); slot 0 handled by t==0 branch in-kernel
    (void)hipMemsetAsync(h0u, 0xFF, (size_t)2 * (STEPS + 1) * H * sizeof(unsigned int), stream);

    ln_kernel<<<dim3(STEPS / 4), dim3(256), 0, stream>>>(batch, lnw, lnb, lnx);
    precomp_kernel<<<dim3(G4 / 64, STEPS / 64), dim3(256), 0, stream>>>(Wih0, bih0, bhh0, lnx, pre);
    recur_kernel<<<dim3(NL0B + NL1B), dim3(TPB), 0, stream>>>(Whh0, Wih1, Whh1, bih1, bhh1,
                                                              pre, h0u, h1u);
    reduce_out<<<dim3(STEPS), dim3(TPB), 0, stream>>>(h1u, fcw, fcb, out);
}

// Round 14
// 8500.446 us; speedup vs baseline: 1.2995x; 1.2995x over previous
//
#include <hip/hip_runtime.h>
#include <math.h>

// LSTMModel: 2048 sequential steps, 2x LSTMCell(H=512), LN(64) front, fc(512->1).
// R13 = R9 base + private per-consumer MAILBOXES (contention-elimination experiment).
// Evidence to date: weights resident (VGPR 36), compute ~0.3us, step ~2.9us = fabric.
// Hypothesis: same-line MALL contention (100s of poll streams per h-line) inflates
// RTT ~4x. Fix: publishers fan out h to each consumer's PRIVATE mailbox (parallel
// 1-store-per-lane via wave shfl broadcast, zero extra barriers); consumers poll
// private lines (~4 streams/line). Ring depth 4; consumer re-poisons after read
// (WAR-safe: lead<=2, re-poison drained by same thread's next poll vmcnt(0) before
// the slot's next writer at iter t+3). Shared h0u/h1u kept for L1-h0 feed + output.

#define H      512
#define G4     2048
#define WIN    64
#define STEPS  2048
#define NL0B   64      // layer-0 blocks (8 units each)
#define NL1B   128     // layer-1 blocks (4 units each)
#define TPB    512
#define POISON 0xFFFFFFFFu

typedef unsigned int u32x4 __attribute__((ext_vector_type(4)));
typedef float        f32x4 __attribute__((ext_vector_type(4)));

__device__ __forceinline__ float sigf(float x)     { return 1.0f / (1.0f + __expf(-x)); }
__device__ __forceinline__ float tanhfast(float x) { return 2.0f / (1.0f + __expf(-2.0f * x)) - 1.0f; }

// ---- agent-scope helpers (proven sound: issue+wait in ONE asm block) ----
__device__ __forceinline__ u32x4 ld4_sc01(const unsigned int* p) {
    u32x4 v;
    asm volatile("global_load_dwordx4 %0, %1, off sc0 sc1\n\ts_waitcnt vmcnt(0)"
                 : "=&v"(v) : "v"(p));
    return v;
}
__device__ __forceinline__ void st1_sc01(unsigned int* p, unsigned int v) {
    asm volatile("global_store_dword %0, %1, off sc0 sc1" :: "v"(p), "v"(v));
}
__device__ __forceinline__ void st4_sc01(unsigned int* p, u32x4 v) {
    asm volatile("global_store_dwordx4 %0, %1, off sc0 sc1" :: "v"(p), "v"(v));
}
__device__ __forceinline__ bool ok4(u32x4 v) {
    return v.x != POISON && v.y != POISON && v.z != POISON && v.w != POISON;
}
__device__ __forceinline__ void lds_put4(float* dst, u32x4 v) {
    float4 f;
    f.x = __uint_as_float(v.x); f.y = __uint_as_float(v.y);
    f.z = __uint_as_float(v.z); f.w = __uint_as_float(v.w);
    *(float4*)dst = f;
}

// ---------------- LayerNorm over sliding windows (parallel over t) ----------------
__global__ void ln_kernel(const float* __restrict__ batch, const float* __restrict__ lnw,
                          const float* __restrict__ lnb, float* __restrict__ lnx) {
    int wave = threadIdx.x >> 6;
    int lane = threadIdx.x & 63;
    int t = blockIdx.x * 4 + wave;
    int src = t - 63 + lane;
    float v = (src >= 0) ? batch[src] : 0.0f;
    float s = v, ss = v * v;
    #pragma unroll
    for (int m = 32; m >= 1; m >>= 1) { s += __shfl_xor(s, m); ss += __shfl_xor(ss, m); }
    float mu   = s * (1.0f / 64.0f);
    float var  = ss * (1.0f / 64.0f) - mu * mu;
    float rstd = rsqrtf(var + 1e-5f);
    lnx[t * WIN + lane] = (v - mu) * rstd * lnw[lane] + lnb[lane];
}

// ---- precomp, UNIT-MAJOR layout: pre[t*2048 + unit*4 + gate] ----
__global__ __launch_bounds__(256) void precomp_kernel(
    const float* __restrict__ Wih0, const float* __restrict__ bih0,
    const float* __restrict__ bhh0, const float* __restrict__ lnx,
    float* __restrict__ pre) {
    __shared__ float Wt[64][65];
    __shared__ float Xt[64][64];
    int r0 = blockIdx.x * 64;
    int t0 = blockIdx.y * 64;
    for (int i = threadIdx.x; i < 4096; i += 256) Wt[i >> 6][i & 63] = Wih0[r0 * 64 + i];
    for (int i = threadIdx.x; i < 4096; i += 256) Xt[i >> 6][i & 63] = lnx[t0 * 64 + i];
    __syncthreads();
    int lane = threadIdx.x & 63;
    int wv   = threadIdx.x >> 6;
    int row  = r0 + lane;                      // gate-major: gate*512 + unit
    int oidx = (row & 511) * 4 + (row >> 9);   // unit-major: unit*4 + gate
    float bias = bih0[row] + bhh0[row];
    for (int j = 0; j < 16; ++j) {
        int tl = wv * 16 + j;
        float acc = bias;
        #pragma unroll 8
        for (int k = 0; k < 64; ++k) acc += Wt[lane][k] * Xt[tl][k];
        pre[(size_t)(t0 + tl) * G4 + oidx] = acc;
    }
}

// ---------------- persistent recurrent kernel with private mailboxes ----------------
__global__ __launch_bounds__(TPB) void recur_kernel(
    const float* __restrict__ Whh0,
    const float* __restrict__ Wih1, const float* __restrict__ Whh1,
    const float* __restrict__ bih1, const float* __restrict__ bhh1,
    const float* __restrict__ pre,
    unsigned int* h0u, unsigned int* h1u,   // shared histories [STEPS+1][H]
    unsigned int* M0,  unsigned int* M1) {  // mailboxes [NL0B][4][H] / [NL1B][4][H]
    const int tid = threadIdx.x;
    const int s   = tid & 31;
    const int LG  = tid >> 5;    // 16 lane-groups of 32
    u32x4 poi; poi.x = POISON; poi.y = POISON; poi.z = POISON; poi.w = POISON;

    if (blockIdx.x < NL0B) {
        // -------- layer-0: 8 units/block; unit = wave; 2 rows/lane-group --------
        __shared__ float hA[2][H];
        const int b  = blockIdx.x;
        const int u0 = b * 8;
        const int uw = tid >> 6;              // wave index = unit-local
        float w0[2][16];
        #pragma unroll
        for (int j = 0; j < 2; ++j) {
            int r   = 2 * LG + j;
            int row = (r & 3) * H + u0 + (r >> 2);
            #pragma unroll
            for (int i = 0; i < 16; ++i) w0[j][i] = Whh0[(size_t)row * H + i * 32 + s];
        }
        float c0 = 0.0f;

        for (int t = 0; t < STEPS; ++t) {
            const int pb = t & 1;
            // pre for this wave's unit (wave-uniform broadcast load)
            f32x4 prv = *(const f32x4*)(pre + (size_t)t * G4 + (u0 + uw) * 4);
            if (tid < 128) {
                if (t > 0) {
                    unsigned int* m = M0 + (size_t)b * 4 * H + (size_t)(t & 3) * H + tid * 4;
                    u32x4 v;
                    do { v = ld4_sc01(m); } while (!ok4(v));
                    lds_put4(&hA[pb][tid * 4], v);
                    st4_sc01(m, poi);          // re-poison (drained by next poll's vmcnt0)
                } else {
                    *(float4*)&hA[pb][tid * 4] = make_float4(0.f, 0.f, 0.f, 0.f);
                }
            }
            __syncthreads();

            float acc0 = 0.0f, acc1 = 0.0f;
            #pragma unroll
            for (int i = 0; i < 16; ++i) {
                float hv = hA[pb][i * 32 + s];
                acc0 += w0[0][i] * hv;
                acc1 += w0[1][i] * hv;
            }
            #pragma unroll
            for (int m = 16; m >= 1; m >>= 1) {
                acc0 += __shfl_xor(acc0, m);
                acc1 += __shfl_xor(acc1, m);
            }
            // lower half-wave group: gates i,f ; upper (lane 32): g,o
            float gacc = __shfl(acc0, 32);
            float oacc = __shfl(acc1, 32);
            float hnew = 0.0f;
            if ((tid & 63) == 0) {
                float iv = sigf(acc0 + prv.x);
                float fv = sigf(acc1 + prv.y);
                float gv = tanhfast(gacc + prv.z);
                float ov = sigf(oacc + prv.w);
                c0 = fv * c0 + iv * gv;
                hnew = ov * tanhfast(c0);
            }
            // fan-out: wave-broadcast h, then each lane stores to its consumer's mailbox
            unsigned int hb = __shfl(__float_as_uint(hnew), 0);
            const int lane = tid & 63;
            st1_sc01(M0 + (size_t)lane * 4 * H + (size_t)((t + 1) & 3) * H + u0 + uw, hb);
            if (lane == 0)   // shared history for L1 consumers
                st1_sc01(h0u + (size_t)(t + 1) * H + u0 + uw, hb);
        }
    } else {
        // -------- layer-1: 4 units/block; 1 row/lane-group; LDS gate exchange --------
        __shared__ float hA2[2][H];
        __shared__ float hB2[2][H];
        __shared__ float glds[16];
        const int b1 = blockIdx.x - NL0B;
        const int u0 = b1 * 4;
        const int row = (LG & 3) * H + u0 + (LG >> 2);
        float w1[16], w2[16];
        #pragma unroll
        for (int i = 0; i < 16; ++i) {
            w1[i] = Wih1[(size_t)row * H + i * 32 + s];
            w2[i] = Whh1[(size_t)row * H + i * 32 + s];
        }
        const float rbias = bih1[row] + bhh1[row];
        float c1 = 0.0f;

        for (int t = 0; t < STEPS; ++t) {
            const int pb = t & 1;
            if (tid < 128) {
                const unsigned int* pa = h0u + (size_t)(t + 1) * H + tid * 4;
                if (t > 0) {
                    // self-chain first: private h1 mailbox
                    unsigned int* m = M1 + (size_t)b1 * 4 * H + (size_t)(t & 3) * H + tid * 4;
                    u32x4 vb;
                    do { vb = ld4_sc01(m); } while (!ok4(vb));
                    lds_put4(&hB2[pb][tid * 4], vb);
                    st4_sc01(m, poi);          // re-poison
                    // h0 (published ~1 step earlier; usually first-try)
                    u32x4 va;
                    do { va = ld4_sc01(pa); } while (!ok4(va));
                    lds_put4(&hA2[pb][tid * 4], va);
                } else {
                    u32x4 va;
                    do { va = ld4_sc01(pa); } while (!ok4(va));
                    lds_put4(&hA2[pb][tid * 4], va);
                    *(float4*)&hB2[pb][tid * 4] = make_float4(0.f, 0.f, 0.f, 0.f);
                }
            }
            __syncthreads();

            float acc = 0.0f;
            #pragma unroll
            for (int i = 0; i < 16; ++i)
                acc += w1[i] * hA2[pb][i * 32 + s] + w2[i] * hB2[pb][i * 32 + s];
            #pragma unroll
            for (int m = 16; m >= 1; m >>= 1) acc += __shfl_xor(acc, m);
            if (s == 0) glds[LG] = acc + rbias;
            __syncthreads();

            float hnew = 0.0f;
            if (tid < 4) {
                float iv = sigf(glds[4 * tid + 0]);
                float fv = sigf(glds[4 * tid + 1]);
                float gv = tanhfast(glds[4 * tid + 2]);
                float ov = sigf(glds[4 * tid + 3]);
                c1 = fv * c1 + iv * gv;
                hnew = ov * tanhfast(c1);
                st1_sc01(h1u + (size_t)(t + 1) * H + u0 + tid, __float_as_uint(hnew));
            }
            // fan-out via wave 0: build x4 packet from lanes 0-3, 2 consumers/lane
            if (tid < 64) {
                unsigned int hbb = __float_as_uint(hnew);
                u32x4 pk;
                pk.x = __shfl(hbb, 0); pk.y = __shfl(hbb, 1);
                pk.z = __shfl(hbb, 2); pk.w = __shfl(hbb, 3);
                unsigned int* base = M1 + (size_t)(tid * 2) * 4 * H
                                        + (size_t)((t + 1) & 3) * H + u0;
                st4_sc01(base, pk);
                st4_sc01(base + 4 * H, pk);
            }
        }
    }
}

// ---------------- out[t] = fc(relu(h1[t+1])) from the h1 history ----------------
__global__ __launch_bounds__(TPB) void reduce_out(
    const unsigned int* __restrict__ h1u, const float* __restrict__ fcw,
    const float* __restrict__ fcb, float* __restrict__ out) {
    int t = blockIdx.x;
    int tid = threadIdx.x;               // 512 threads
    float h = __uint_as_float(h1u[(size_t)(t + 1) * H + tid]);
    float v = fmaxf(h, 0.0f) * fcw[tid];
    #pragma unroll
    for (int m = 32; m >= 1; m >>= 1) v += __shfl_xor(v, m);
    __shared__ float ws8[8];
    if ((tid & 63) == 0) ws8[tid >> 6] = v;
    __syncthreads();
    if (tid == 0) {
        float ssum = 0.0f;
        #pragma unroll
        for (int i = 0; i < 8; ++i) ssum += ws8[i];
        out[t] = ssum + fcb[0];
    }
}

extern "C" void kernel_launch(void* const* d_in, const int* in_sizes, int n_in,
                              void* d_out, int out_size, void* d_ws, size_t ws_size,
                              hipStream_t stream) {
    const float* batch = (const float*)d_in[0];
    const float* Wih0  = (const float*)d_in[1];
    const float* Whh0  = (const float*)d_in[2];
    const float* bih0  = (const float*)d_in[3];
    const float* bhh0  = (const float*)d_in[4];
    const float* Wih1  = (const float*)d_in[5];
    const float* Whh1  = (const float*)d_in[6];
    const float* bih1  = (const float*)d_in[7];
    const float* bhh1  = (const float*)d_in[8];
    const float* lnw   = (const float*)d_in[9];
    const float* lnb   = (const float*)d_in[10];
    const float* fcw   = (const float*)d_in[11];
    const float* fcb   = (const float*)d_in[12];
    float* out = (float*)d_out;

    // workspace layout (~27 MB); poisoned region is contiguous
    float*        ws   = (float*)d_ws;
    float*        pre  = ws;                                   // 2048*2048 (16 MB)
    float*        lnx  = pre + (size_t)STEPS * G4;             // 2048*64
    unsigned int* h0u  = (unsigned int*)(lnx + (size_t)STEPS * WIN);  // 2049*512
    unsigned int* h1u  = h0u + (size_t)(STEPS + 1) * H;        // 2049*512
    unsigned int* M0   = h1u + (size_t)(STEPS + 1) * H;        // 64*4*512
    unsigned int* M1   = M0 + (size_t)NL0B * 4 * H;            // 128*4*512
    size_t poison_u32  = (size_t)2 * (STEPS + 1) * H + (size_t)(NL0B + NL1B) * 4 * H;

    (void)hipMemsetAsync(h0u, 0xFF, poison_u32 * sizeof(unsigned int), stream);

    ln_kernel<<<dim3(STEPS / 4), dim3(256), 0, stream>>>(batch, lnw, lnb, lnx);
    precomp_kernel<<<dim3(G4 / 64, STEPS / 64), dim3(256), 0, stream>>>(Wih0, bih0, bhh0, lnx, pre);
    recur_kernel<<<dim3(NL0B + NL1B), dim3(TPB), 0, stream>>>(Whh0, Wih1, Whh1, bih1, bhh1,
                                                              pre, h0u, h1u, M0, M1);
    reduce_out<<<dim3(STEPS), dim3(TPB), 0, stream>>>(h1u, fcw, fcb, out);
}

// Round 15
// 4996.642 us; speedup vs baseline: 2.2108x; 1.7012x over previous
//
#include <hip/hip_runtime.h>
#include <math.h>

// LSTMModel: 2048 sequential steps, 2x LSTMCell(H=512), LN(64) front, fc(512->1).
// R14 = R9 (best: 5.95ms) + ONE surgical change: L1's two poll loads (h1 self-chain
// + h0 feed) fused into a single asm block with one vmcnt(0) -> 1 MALL RTT per check
// iteration instead of 2 serial RTTs. Zero added traffic (same 2 loads/iter).
// Rationale: global critical path is the h1 self-chain (L0 runs ahead unboundedly,
// append-only history); R9's L1 serial double-wait made L1 step ~2x RTT ~= 2.9us.
// Soundness: issue+wait live in ONE asm block (R8/R11/R12 lesson); re-polling an
// already-valid packet is harmless (words are monotonic poison->value).

#define H      512
#define G4     2048
#define WIN    64
#define STEPS  2048
#define NL0B   64      // layer-0 blocks (8 units each)
#define NL1B   128     // layer-1 blocks (4 units each)
#define TPB    512
#define POISON 0xFFFFFFFFu

typedef unsigned int u32x4 __attribute__((ext_vector_type(4)));
typedef float        f32x4 __attribute__((ext_vector_type(4)));

__device__ __forceinline__ float sigf(float x)     { return 1.0f / (1.0f + __expf(-x)); }
__device__ __forceinline__ float tanhfast(float x) { return 2.0f / (1.0f + __expf(-2.0f * x)) - 1.0f; }

// ---- agent-scope helpers (issue+wait in ONE asm block -> sound) ----
__device__ __forceinline__ u32x4 ld4_sc01(const unsigned int* p) {
    u32x4 v;
    asm volatile("global_load_dwordx4 %0, %1, off sc0 sc1\n\ts_waitcnt vmcnt(0)"
                 : "=&v"(v) : "v"(p));
    return v;
}
// dual-packet load: both in flight together, one wait -> 1 RTT for the pair
__device__ __forceinline__ void ld4x2_sc01(const unsigned int* pa, const unsigned int* pb,
                                           u32x4& va, u32x4& vb) {
    asm volatile("global_load_dwordx4 %0, %2, off sc0 sc1\n\t"
                 "global_load_dwordx4 %1, %3, off sc0 sc1\n\t"
                 "s_waitcnt vmcnt(0)"
                 : "=&v"(va), "=&v"(vb) : "v"(pa), "v"(pb));
}
__device__ __forceinline__ void st1_sc01(unsigned int* p, unsigned int v) {
    asm volatile("global_store_dword %0, %1, off sc0 sc1" :: "v"(p), "v"(v));
}
__device__ __forceinline__ bool ok4(u32x4 v) {
    return v.x != POISON && v.y != POISON && v.z != POISON && v.w != POISON;
}
__device__ __forceinline__ void lds_put4(float* dst, u32x4 v) {
    float4 f;
    f.x = __uint_as_float(v.x); f.y = __uint_as_float(v.y);
    f.z = __uint_as_float(v.z); f.w = __uint_as_float(v.w);
    *(float4*)dst = f;
}

// ---------------- LayerNorm over sliding windows (parallel over t) ----------------
__global__ void ln_kernel(const float* __restrict__ batch, const float* __restrict__ lnw,
                          const float* __restrict__ lnb, float* __restrict__ lnx) {
    int wave = threadIdx.x >> 6;
    int lane = threadIdx.x & 63;
    int t = blockIdx.x * 4 + wave;
    int src = t - 63 + lane;
    float v = (src >= 0) ? batch[src] : 0.0f;
    float s = v, ss = v * v;
    #pragma unroll
    for (int m = 32; m >= 1; m >>= 1) { s += __shfl_xor(s, m); ss += __shfl_xor(ss, m); }
    float mu   = s * (1.0f / 64.0f);
    float var  = ss * (1.0f / 64.0f) - mu * mu;
    float rstd = rsqrtf(var + 1e-5f);
    lnx[t * WIN + lane] = (v - mu) * rstd * lnw[lane] + lnb[lane];
}

// ---- precomp, UNIT-MAJOR layout: pre[t*2048 + unit*4 + gate] ----
__global__ __launch_bounds__(256) void precomp_kernel(
    const float* __restrict__ Wih0, const float* __restrict__ bih0,
    const float* __restrict__ bhh0, const float* __restrict__ lnx,
    float* __restrict__ pre) {
    __shared__ float Wt[64][65];
    __shared__ float Xt[64][64];
    int r0 = blockIdx.x * 64;
    int t0 = blockIdx.y * 64;
    for (int i = threadIdx.x; i < 4096; i += 256) Wt[i >> 6][i & 63] = Wih0[r0 * 64 + i];
    for (int i = threadIdx.x; i < 4096; i += 256) Xt[i >> 6][i & 63] = lnx[t0 * 64 + i];
    __syncthreads();
    int lane = threadIdx.x & 63;
    int wv   = threadIdx.x >> 6;
    int row  = r0 + lane;                      // gate-major: gate*512 + unit
    int oidx = (row & 511) * 4 + (row >> 9);   // unit-major: unit*4 + gate
    float bias = bih0[row] + bhh0[row];
    for (int j = 0; j < 16; ++j) {
        int tl = wv * 16 + j;
        float acc = bias;
        #pragma unroll 8
        for (int k = 0; k < 64; ++k) acc += Wt[lane][k] * Xt[tl][k];
        pre[(size_t)(t0 + tl) * G4 + oidx] = acc;
    }
}

// ---------------- persistent recurrent kernel ----------------
__global__ __launch_bounds__(TPB) void recur_kernel(
    const float* __restrict__ Whh0,
    const float* __restrict__ Wih1, const float* __restrict__ Whh1,
    const float* __restrict__ bih1, const float* __restrict__ bhh1,
    const float* __restrict__ pre,
    unsigned int* h0u, unsigned int* h1u) { // [STEPS+1][H] histories, NaN-poisoned
    const int tid = threadIdx.x;
    const int s   = tid & 31;
    const int LG  = tid >> 5;    // 16 lane-groups of 32

    if (blockIdx.x < NL0B) {
        // -------- layer-0: 8 units/block; unit = wave; 2 rows/lane-group --------
        __shared__ float hA[2][H];
        const int u0 = blockIdx.x * 8;
        const int u  = tid >> 6;              // wave index = unit-local
        float w0[2][16];
        #pragma unroll
        for (int j = 0; j < 2; ++j) {
            int r   = 2 * LG + j;
            int row = (r & 3) * H + u0 + (r >> 2);
            #pragma unroll
            for (int i = 0; i < 16; ++i) w0[j][i] = Whh0[(size_t)row * H + i * 32 + s];
        }
        float c0 = 0.0f;

        for (int t = 0; t < STEPS; ++t) {
            const int pb = t & 1;
            // pre for this wave's unit (wave-uniform broadcast load; hides under poll)
            f32x4 prv = *(const f32x4*)(pre + (size_t)t * G4 + (u0 + u) * 4);
            if (tid < 128) {
                if (t > 0) {
                    const unsigned int* p = h0u + (size_t)t * H + tid * 4;
                    u32x4 v;
                    do { v = ld4_sc01(p); } while (!ok4(v));
                    lds_put4(&hA[pb][tid * 4], v);
                } else {
                    *(float4*)&hA[pb][tid * 4] = make_float4(0.f, 0.f, 0.f, 0.f);
                }
            }
            __syncthreads();

            float acc0 = 0.0f, acc1 = 0.0f;
            #pragma unroll
            for (int i = 0; i < 16; ++i) {
                float hv = hA[pb][i * 32 + s];
                acc0 += w0[0][i] * hv;
                acc1 += w0[1][i] * hv;
            }
            #pragma unroll
            for (int m = 16; m >= 1; m >>= 1) {
                acc0 += __shfl_xor(acc0, m);
                acc1 += __shfl_xor(acc1, m);
            }
            // lower half-wave group: gates i,f ; upper (lane 32): g,o
            float gacc = __shfl(acc0, 32);
            float oacc = __shfl(acc1, 32);
            if ((tid & 63) == 0) {
                float iv = sigf(acc0 + prv.x);
                float fv = sigf(acc1 + prv.y);
                float gv = tanhfast(gacc + prv.z);
                float ov = sigf(oacc + prv.w);
                c0 = fv * c0 + iv * gv;
                float hnew = ov * tanhfast(c0);
                st1_sc01(h0u + (size_t)(t + 1) * H + u0 + u, __float_as_uint(hnew));
            }
        }
    } else {
        // -------- layer-1: 4 units/block; 1 row/lane-group; LDS gate exchange --------
        __shared__ float hA2[2][H];
        __shared__ float hB2[2][H];
        __shared__ float glds[16];
        const int b1 = blockIdx.x - NL0B;
        const int u0 = b1 * 4;
        const int row = (LG & 3) * H + u0 + (LG >> 2);
        float w1[16], w2[16];
        #pragma unroll
        for (int i = 0; i < 16; ++i) {
            w1[i] = Wih1[(size_t)row * H + i * 32 + s];
            w2[i] = Whh1[(size_t)row * H + i * 32 + s];
        }
        const float rbias = bih1[row] + bhh1[row];
        float c1 = 0.0f;

        for (int t = 0; t < STEPS; ++t) {
            const int pb = t & 1;
            if (tid < 128) {
                const unsigned int* pa = h0u + (size_t)(t + 1) * H + tid * 4;
                if (t > 0) {
                    // DUAL poll: h0 feed + h1 self-chain in flight together, one wait
                    const unsigned int* pbp = h1u + (size_t)t * H + tid * 4;
                    u32x4 va, vb;
                    do { ld4x2_sc01(pa, pbp, va, vb); } while (!(ok4(va) && ok4(vb)));
                    lds_put4(&hA2[pb][tid * 4], va);
                    lds_put4(&hB2[pb][tid * 4], vb);
                } else {
                    u32x4 va;
                    do { va = ld4_sc01(pa); } while (!ok4(va));
                    lds_put4(&hA2[pb][tid * 4], va);
                    *(float4*)&hB2[pb][tid * 4] = make_float4(0.f, 0.f, 0.f, 0.f);
                }
            }
            __syncthreads();

            float acc = 0.0f;
            #pragma unroll
            for (int i = 0; i < 16; ++i)
                acc += w1[i] * hA2[pb][i * 32 + s] + w2[i] * hB2[pb][i * 32 + s];
            #pragma unroll
            for (int m = 16; m >= 1; m >>= 1) acc += __shfl_xor(acc, m);
            if (s == 0) glds[LG] = acc + rbias;
            __syncthreads();
            if (tid < 4) {
                float iv = sigf(glds[4 * tid + 0]);
                float fv = sigf(glds[4 * tid + 1]);
                float gv = tanhfast(glds[4 * tid + 2]);
                float ov = sigf(glds[4 * tid + 3]);
                c1 = fv * c1 + iv * gv;
                float hnew = ov * tanhfast(c1);
                st1_sc01(h1u + (size_t)(t + 1) * H + u0 + tid, __float_as_uint(hnew));
            }
        }
    }
}

// ---------------- out[t] = fc(relu(h1[t+1])) from the h1 history ----------------
__global__ __launch_bounds__(TPB) void reduce_out(
    const unsigned int* __restrict__ h1u, const float* __restrict__ fcw,
    const float* __restrict__ fcb, float* __restrict__ out) {
    int t = blockIdx.x;
    int tid = threadIdx.x;               // 512 threads
    float h = __uint_as_float(h1u[(size_t)(t + 1) * H + tid]);
    float v = fmaxf(h, 0.0f) * fcw[tid];
    #pragma unroll
    for (int m = 32; m >= 1; m >>= 1) v += __shfl_xor(v, m);
    __shared__ float ws8[8];
    if ((tid & 63) == 0) ws8[tid >> 6] = v;
    __syncthreads();
    if (tid == 0) {
        float ssum = 0.0f;
        #pragma unroll
        for (int i = 0; i < 8; ++i) ssum += ws8[i];
        out[t] = ssum + fcb[0];
    }
}

extern "C" void kernel_launch(void* const* d_in, const int* in_sizes, int n_in,
                              void* d_out, int out_size, void* d_ws, size_t ws_size,
                              hipStream_t stream) {
    const float* batch = (const float*)d_in[0];
    const float* Wih0  = (const float*)d_in[1];
    const float* Whh0  = (const float*)d_in[2];
    const float* bih0  = (const float*)d_in[3];
    const float* bhh0  = (const float*)d_in[4];
    const float* Wih1  = (const float*)d_in[5];
    const float* Whh1  = (const float*)d_in[6];
    const float* bih1  = (const float*)d_in[7];
    const float* bhh1  = (const float*)d_in[8];
    const float* lnw   = (const float*)d_in[9];
    const float* lnb   = (const float*)d_in[10];
    const float* fcw   = (const float*)d_in[11];
    const float* fcb   = (const float*)d_in[12];
    float* out = (float*)d_out;

    // workspace layout (~17 MB)
    float*        ws   = (float*)d_ws;
    float*        pre  = ws;                                   // 2048*2048 (16 MB)
    float*        lnx  = pre + (size_t)STEPS * G4;             // 2048*64
    unsigned int* h0u  = (unsigned int*)(lnx + (size_t)STEPS * WIN);  // 2049*512
    unsigned int* h1u  = h0u + (size_t)(STEPS + 1) * H;        // 2049*512

    // poison both h histories (NaN pattern); slot 0 handled by t==0 branch in-kernel
    (void)hipMemsetAsync(h0u, 0xFF, (size_t)2 * (STEPS + 1) * H * sizeof(unsigned int), stream);

    ln_kernel<<<dim3(STEPS / 4), dim3(256), 0, stream>>>(batch, lnw, lnb, lnx);
    precomp_kernel<<<dim3(G4 / 64, STEPS / 64), dim3(256), 0, stream>>>(Wih0, bih0, bhh0, lnx, pre);
    recur_kernel<<<dim3(NL0B + NL1B), dim3(TPB), 0, stream>>>(Whh0, Wih1, Whh1, bih1, bhh1,
                                                              pre, h0u, h1u);
    reduce_out<<<dim3(STEPS), dim3(TPB), 0, stream>>>(h1u, fcw, fcb, out);
}